// Round 10
// baseline (345.652 us; speedup 1.0000x reference)
//
#include <hip/hip_runtime.h>

#define N_NODES 50000
#define N_EDGES 800000
#define IN_DIM 256
#define HID 64
#define OUT_DIM 16
#define GAT_IN 66   // HID + N_PROTO
#define NB_SCAN 196 // 196*256 = 50176 >= N_NODES

typedef unsigned short u16;
typedef unsigned int u32;
typedef __attribute__((ext_vector_type(8))) short s8v;   // 8 bf16 (4 VGPRs)
typedef __attribute__((ext_vector_type(4))) float f4v;   // MFMA accumulator
typedef __attribute__((ext_vector_type(2))) float f2v;   // packed fp32 pair

__device__ __forceinline__ float bf2f(u16 u) {
  union { u32 i; float f; } v; v.i = ((u32)u) << 16; return v.f;
}
__device__ __forceinline__ u16 f2bf(float f) {
  union { float f; u32 i; } v; v.f = f;
  u32 r = v.i + 0x7FFFu + ((v.i >> 16) & 1u);
  return (u16)(r >> 16);
}
__device__ __forceinline__ void split8(const float* uu, s8v& ah, s8v& al) {
  #pragma unroll
  for (int j = 0; j < 8; ++j) {
    u32 bits = __float_as_uint(uu[j]);
    u16 hb = (u16)(bits >> 16);
    ah[j] = (short)hb;
    al[j] = (short)f2bf(uu[j] - bf2f(hb));
  }
}

// ---------------------------------------------------------------------------
// K_PREP: pre-transpose weights into MFMA B-fragment order (bf16, global),
// zero deg[] / gcount. Runs once, ~100 KB of writes.
// haug layout:  m = s*2048 + t*512 + l*8 + j  <->  k = s*32+(l>>4)*8+j,
//               c = t*16+(l&15)      (Win is [k][c], 256x64)
// lin layout:   m = s*8192 + t*512 + l*8 + j  <->  k = s*32+(l>>4)*8+j,
//               j2 = t*16+(l&15)     (W is [k][j2], 66x256, K zero-pad to 96)
// ---------------------------------------------------------------------------
__global__ __launch_bounds__(256) void k_prep(
    const float* __restrict__ Win, const float* __restrict__ Wl,
    const float* __restrict__ Wr, u16* __restrict__ wbT,
    u16* __restrict__ wlT, u16* __restrict__ wrT,
    int* __restrict__ deg, int* __restrict__ gcount)
{
  const int gid = blockIdx.x * 256 + threadIdx.x;
  const int stride = gridDim.x * 256;
  for (int i = gid; i < N_NODES; i += stride) deg[i] = 0;
  if (gid == 0) *gcount = 0;
  for (int m = gid; m < 16384; m += stride) {
    int s = m >> 11, rem = m & 2047;
    int t = rem >> 9, rem2 = rem & 511;
    int l = rem2 >> 3, j = rem2 & 7;
    int k = s * 32 + (l >> 4) * 8 + j;
    int c = t * 16 + (l & 15);
    wbT[m] = f2bf(Win[k * 64 + c]);
  }
  for (int m = gid; m < 24576; m += stride) {
    int s = m >> 13, rem = m & 8191;
    int t = rem >> 9, rem2 = rem & 511;
    int l = rem2 >> 3, j = rem2 & 7;
    int k = s * 32 + (l >> 4) * 8 + j;
    int j2 = t * 16 + (l & 15);
    u16 vl = 0, vr = 0;
    if (k < GAT_IN) {
      vl = f2bf(Wl[k * 256 + j2]);
      vr = f2bf(Wr[k * 256 + j2]);
    }
    wlT[m] = vl;
    wrT[m] = vr;
  }
}

// ---------------------------------------------------------------------------
// K1 (MFMA, no LDS): h = relu(x @ W_in + b_in); sem = cosine sims.
// B-fragments loaded straight from pre-transposed wbT (L2-resident).
// ---------------------------------------------------------------------------
__global__ __launch_bounds__(256) void k_haug(
    const float* __restrict__ x, const u16* __restrict__ wbT,
    const float* __restrict__ bin, const float* __restrict__ proto,
    float* __restrict__ ha)
{
  const int lane = threadIdx.x & 63;
  const int nb = blockIdx.x * 64 + (threadIdx.x >> 6) * 16;
  if (nb >= N_NODES) return;
  const int mrow = lane & 15, q = lane >> 4;

  f4v acc0 = {0.f,0.f,0.f,0.f}, acc1 = {0.f,0.f,0.f,0.f};
  f4v acc2 = {0.f,0.f,0.f,0.f}, acc3 = {0.f,0.f,0.f,0.f};
  const float* xrow = x + (size_t)(nb + mrow) * IN_DIM + q * 8;
  #pragma unroll 2
  for (int s = 0; s < 8; ++s) {
    float4 u0 = *(const float4*)(xrow + s * 32);
    float4 u1 = *(const float4*)(xrow + s * 32 + 4);
    float uu[8] = {u0.x, u0.y, u0.z, u0.w, u1.x, u1.y, u1.z, u1.w};
    s8v ah, al;
    split8(uu, ah, al);
    const u16* wp = wbT + s * 2048 + lane * 8;
    s8v b0 = *(const s8v*)(wp);
    s8v b1 = *(const s8v*)(wp + 512);
    s8v b2 = *(const s8v*)(wp + 1024);
    s8v b3 = *(const s8v*)(wp + 1536);
    acc0 = __builtin_amdgcn_mfma_f32_16x16x32_bf16(ah, b0, acc0, 0, 0, 0);
    acc0 = __builtin_amdgcn_mfma_f32_16x16x32_bf16(al, b0, acc0, 0, 0, 0);
    acc1 = __builtin_amdgcn_mfma_f32_16x16x32_bf16(ah, b1, acc1, 0, 0, 0);
    acc1 = __builtin_amdgcn_mfma_f32_16x16x32_bf16(al, b1, acc1, 0, 0, 0);
    acc2 = __builtin_amdgcn_mfma_f32_16x16x32_bf16(ah, b2, acc2, 0, 0, 0);
    acc2 = __builtin_amdgcn_mfma_f32_16x16x32_bf16(al, b2, acc2, 0, 0, 0);
    acc3 = __builtin_amdgcn_mfma_f32_16x16x32_bf16(ah, b3, acc3, 0, 0, 0);
    acc3 = __builtin_amdgcn_mfma_f32_16x16x32_bf16(al, b3, acc3, 0, 0, 0);
  }

  float bt[4], p0t[4], p1t[4];
  #pragma unroll
  for (int t = 0; t < 4; ++t) {
    bt[t]  = bin[t * 16 + mrow];
    p0t[t] = proto[t * 16 + mrow];
    p1t[t] = proto[64 + t * 16 + mrow];
  }
  float np0 = 0.f, np1 = 0.f;
  #pragma unroll
  for (int t = 0; t < 4; ++t) { np0 += p0t[t] * p0t[t]; np1 += p1t[t] * p1t[t]; }
  #pragma unroll
  for (int mm = 1; mm < 16; mm <<= 1) {
    np0 += __shfl_xor(np0, mm); np1 += __shfl_xor(np1, mm);
  }
  const float ip0 = 1.f / (sqrtf(np0) + 1e-12f);
  const float ip1 = 1.f / (sqrtf(np1) + 1e-12f);

  float hcol[4][4];
  #pragma unroll
  for (int r = 0; r < 4; ++r) {
    hcol[0][r] = fmaxf(acc0[r] + bt[0], 0.f);
    hcol[1][r] = fmaxf(acc1[r] + bt[1], 0.f);
    hcol[2][r] = fmaxf(acc2[r] + bt[2], 0.f);
    hcol[3][r] = fmaxf(acc3[r] + bt[3], 0.f);
  }
  #pragma unroll
  for (int r = 0; r < 4; ++r) {
    float r0 = 0.f, r1 = 0.f, r2 = 0.f;
    #pragma unroll
    for (int t = 0; t < 4; ++t) {
      float h = hcol[t][r];
      r0 += h * h; r1 += h * p0t[t]; r2 += h * p1t[t];
    }
    #pragma unroll
    for (int mm = 1; mm < 16; mm <<= 1) {
      r0 += __shfl_xor(r0, mm); r1 += __shfl_xor(r1, mm); r2 += __shfl_xor(r2, mm);
    }
    float* row = ha + (size_t)(nb + q * 4 + r) * 68;
    #pragma unroll
    for (int t = 0; t < 4; ++t) row[t * 16 + mrow] = hcol[t][r];
    if (mrow == 0) {
      float hi = 1.f / (sqrtf(r0) + 1e-12f);
      row[64] = r1 * hi * ip0;
      row[65] = r2 * hi * ip1;
    }
  }
}

// ---------------------------------------------------------------------------
// K2 (MFMA, no LDS): xl (or xr) = ha @ W + b -> bf16 [n][256], B from wT.
// ---------------------------------------------------------------------------
__global__ __launch_bounds__(256) void k_lin(
    const float* __restrict__ ha, const u16* __restrict__ wT,
    const float* __restrict__ b, u16* __restrict__ outp)
{
  const int lane = threadIdx.x & 63;
  const int nb = blockIdx.x * 64 + (threadIdx.x >> 6) * 16;
  if (nb >= N_NODES) return;
  const int mrow = lane & 15, q = lane >> 4;

  f4v acc[16];
  #pragma unroll
  for (int t = 0; t < 16; ++t) acc[t] = (f4v){0.f, 0.f, 0.f, 0.f};

  const float* row = ha + (size_t)(nb + mrow) * 68;
  #pragma unroll
  for (int s = 0; s < 3; ++s) {
    float uu[8];
    if (s < 2) {
      float4 u0 = *(const float4*)(row + s * 32 + q * 8);
      float4 u1 = *(const float4*)(row + s * 32 + q * 8 + 4);
      uu[0]=u0.x; uu[1]=u0.y; uu[2]=u0.z; uu[3]=u0.w;
      uu[4]=u1.x; uu[5]=u1.y; uu[6]=u1.z; uu[7]=u1.w;
    } else {
      #pragma unroll
      for (int j = 0; j < 8; ++j) uu[j] = 0.f;
      if (q == 0) { uu[0] = row[64]; uu[1] = row[65]; }
    }
    s8v ah, al;
    split8(uu, ah, al);
    const u16* wp = wT + s * 8192 + lane * 8;
    #pragma unroll
    for (int t = 0; t < 16; ++t) {
      s8v bv = *(const s8v*)(wp + t * 512);
      acc[t] = __builtin_amdgcn_mfma_f32_16x16x32_bf16(ah, bv, acc[t], 0, 0, 0);
      acc[t] = __builtin_amdgcn_mfma_f32_16x16x32_bf16(al, bv, acc[t], 0, 0, 0);
    }
  }

  #pragma unroll
  for (int t = 0; t < 16; ++t) {
    float bc = b[t * 16 + mrow];
    #pragma unroll
    for (int r = 0; r < 4; ++r) {
      outp[(size_t)(nb + q * 4 + r) * 256 + t * 16 + mrow] = f2bf(acc[t][r] + bc);
    }
  }
}

// --------------------------- CSR construction ------------------------------
__device__ __forceinline__ int probe_i64(const void* ei) {
  const long long* e64 = (const long long*)ei;
  int ok = 1;
  #pragma unroll
  for (int k = 0; k < 16; k++) {
    long long v = e64[k];
    if (v < 0 || v >= N_NODES) { ok = 0; break; }
  }
  return ok;
}

__global__ void k_hist(const void* __restrict__ ei, int* __restrict__ deg) {
  __shared__ int isl_s;
  if (threadIdx.x == 0) isl_s = probe_i64(ei);
  __syncthreads();
  int e = blockIdx.x * 256 + threadIdx.x;
  if (e >= N_EDGES) return;
  int d;
  if (isl_s) d = (int)((const long long*)ei)[N_EDGES + e];
  else       d = ((const int*)ei)[N_EDGES + e];
  if ((unsigned)d < N_NODES) atomicAdd(&deg[d], 1);
}

__global__ __launch_bounds__(256) void k_scan1(
    const int* __restrict__ deg, int* __restrict__ gcount,
    int* __restrict__ beg, int* __restrict__ end, int* __restrict__ cur)
{
  const int t = threadIdx.x;
  const int lane = t & 63;
  const int i = blockIdx.x * 256 + t;
  int v = (i < N_NODES) ? deg[i] : 0;
  int inc = v;
  #pragma unroll
  for (int d = 1; d < 64; d <<= 1) {
    int sv = __shfl_up(inc, d);
    if (lane >= d) inc += sv;
  }
  __shared__ int wtot[4];
  __shared__ int base_s;
  if (lane == 63) wtot[t >> 6] = inc;
  __syncthreads();
  if (t == 0) {
    int tot = wtot[0] + wtot[1] + wtot[2] + wtot[3];
    base_s = atomicAdd(gcount, tot);
  }
  __syncthreads();
  int add = base_s;
  for (int w = 0; w < (t >> 6); ++w) add += wtot[w];
  int ex = add + inc - v;
  if (i < N_NODES) { beg[i] = ex; cur[i] = ex; end[i] = ex + v; }
}

__global__ void k_scatter(const void* __restrict__ ei,
                          int* __restrict__ cur, int* __restrict__ esrc) {
  __shared__ int isl_s;
  if (threadIdx.x == 0) isl_s = probe_i64(ei);
  __syncthreads();
  int e = blockIdx.x * 256 + threadIdx.x;
  if (e >= N_EDGES) return;
  int s, d;
  if (isl_s) {
    s = (int)((const long long*)ei)[e];
    d = (int)((const long long*)ei)[N_EDGES + e];
  } else {
    s = ((const int*)ei)[e];
    d = ((const int*)ei)[N_EDGES + e];
  }
  if ((unsigned)d >= N_NODES) return;
  if ((unsigned)s >= N_NODES) s = 0;
  int p = atomicAdd(&cur[d], 1);
  if ((unsigned)p < N_EDGES) esrc[p] = s;
}

// ---------------------------------------------------------------------------
// K5: per-dst-node softmax aggregation (no max-shift; clamp 60), unroll-8
// with packed-fp32 (f2v) edge math, + head-mean + relu + classifier.
// ---------------------------------------------------------------------------
__device__ __forceinline__ float edge_gp(uint2 rv, f2v xr01, f2v xr23,
                                         f2v av01, f2v av23,
                                         f2v& x01, f2v& x23) {
  x01.x = __uint_as_float(rv.x << 16);
  x01.y = __uint_as_float(rv.x & 0xffff0000u);
  x23.x = __uint_as_float(rv.y << 16);
  x23.y = __uint_as_float(rv.y & 0xffff0000u);
  f2v t01 = x01 + xr01, t23 = x23 + xr23;
  t01 = __builtin_elementwise_max(t01, t01 * 0.2f);
  t23 = __builtin_elementwise_max(t23, t23 * 0.2f);
  f2v d = av01 * t01 + av23 * t23;
  return d.x + d.y;
}

template <int INLINE_XR>
__global__ __launch_bounds__(256) void k_agg(
    const u16* __restrict__ xls, const u16* __restrict__ xrs,
    const float* __restrict__ ha, const float* __restrict__ Wr,
    const float* __restrict__ br,
    const int* __restrict__ esrc, const int* __restrict__ beg,
    const int* __restrict__ end,
    const float* __restrict__ att, const float* __restrict__ gbias,
    const float* __restrict__ wcls, const float* __restrict__ bcls,
    float* __restrict__ out)
{
  __shared__ u16 wr[INLINE_XR ? GAT_IN * 256 : 64];
  if (INLINE_XR) {
    for (int m = threadIdx.x; m < GAT_IN * 256; m += 256) wr[m] = f2bf(Wr[m]);
    __syncthreads();
  }
  const int lane = threadIdx.x & 63;
  const int n = blockIdx.x * 4 + (threadIdx.x >> 6);
  if (n >= N_NODES) return;

  float4 avr = *(const float4*)(att + lane * 4);
  const f2v av01 = {avr.x, avr.y}, av23 = {avr.z, avr.w};

  f2v xr01, xr23;
  if (INLINE_XR) {
    float4 bv = *(const float4*)(br + lane * 4);
    float y0 = bv.x, y1 = bv.y, y2 = bv.z, y3 = bv.w;
    const float* hrow = ha + (size_t)n * 68;
    for (int i = 0; i < GAT_IN; ++i) {
      ushort4 wv = *(const ushort4*)&wr[i * 256 + lane * 4];
      float hv = hrow[i];
      y0 += hv * bf2f(wv.x); y1 += hv * bf2f(wv.y);
      y2 += hv * bf2f(wv.z); y3 += hv * bf2f(wv.w);
    }
    xr01 = (f2v){y0, y1}; xr23 = (f2v){y2, y3};
  } else {
    uint2 qv = *(const uint2*)(xrs + (size_t)n * 256 + lane * 4);
    xr01.x = __uint_as_float(qv.x << 16);
    xr01.y = __uint_as_float(qv.x & 0xffff0000u);
    xr23.x = __uint_as_float(qv.y << 16);
    xr23.y = __uint_as_float(qv.y & 0xffff0000u);
  }

  int kb = beg[n], ke = end[n];
  if (kb < 0) kb = 0;
  if (ke > N_EDGES) ke = N_EDGES;
  int dg = ke - kb; if (dg < 0) dg = 0;

  float l_;
  f2v c01, c23;
  {  // self-loop
    uint2 rv = *(const uint2*)(xls + (size_t)n * 256 + lane * 4);
    f2v x01, x23;
    float g = edge_gp(rv, xr01, xr23, av01, av23, x01, x23);
    g += __shfl_xor(g, 1); g += __shfl_xor(g, 2);
    g += __shfl_xor(g, 4); g += __shfl_xor(g, 8);
    float a = __expf(fminf(g, 60.f));
    l_ = a; c01 = x01 * a; c23 = x23 * a;
  }

  for (int e = 0; e < dg; e += 8) {
    const int rem = dg - e;
    const int i0 = kb + e;
    int su[8];
    su[0] = esrc[i0];
    #pragma unroll
    for (int u = 1; u < 8; ++u) su[u] = (u < rem) ? esrc[i0 + u] : su[0];
    uint2 rv[8];
    #pragma unroll
    for (int u = 0; u < 8; ++u)
      rv[u] = *(const uint2*)(xls + (size_t)su[u] * 256 + lane * 4);
    f2v x01[8], x23[8];
    float g[8];
    #pragma unroll
    for (int u = 0; u < 8; ++u)
      g[u] = edge_gp(rv[u], xr01, xr23, av01, av23, x01[u], x23[u]);
    #pragma unroll
    for (int d = 1; d < 16; d <<= 1) {
      #pragma unroll
      for (int u = 0; u < 8; ++u) g[u] += __shfl_xor(g[u], d);
    }
    #pragma unroll
    for (int u = 0; u < 8; ++u) {
      float a = (u < rem) ? __expf(fminf(g[u], 60.f)) : 0.f;
      l_ += a;
      c01 += x01[u] * a;
      c23 += x23[u] * a;
    }
  }

  float inv = 1.f / (l_ + 1e-16f);
  float v0 = c01.x * inv, v1 = c01.y * inv, v2 = c23.x * inv, v3 = c23.y * inv;
  v0 += __shfl_xor(v0, 16); v0 += __shfl_xor(v0, 32);
  v1 += __shfl_xor(v1, 16); v1 += __shfl_xor(v1, 32);
  v2 += __shfl_xor(v2, 16); v2 += __shfl_xor(v2, 32);
  v3 += __shfl_xor(v3, 16); v3 += __shfl_xor(v3, 32);
  const int g4 = (lane & 15) * 4;
  const int h = lane >> 4;
  float4 gb = *(const float4*)(gbias + g4);
  v0 = fmaxf(0.25f * v0 + gb.x, 0.f);
  v1 = fmaxf(0.25f * v1 + gb.y, 0.f);
  v2 = fmaxf(0.25f * v2 + gb.z, 0.f);
  v3 = fmaxf(0.25f * v3 + gb.w, 0.f);
  float4 w0 = *(const float4*)(wcls + (g4 + 0) * 16 + h * 4);
  float4 w1 = *(const float4*)(wcls + (g4 + 1) * 16 + h * 4);
  float4 w2 = *(const float4*)(wcls + (g4 + 2) * 16 + h * 4);
  float4 w3 = *(const float4*)(wcls + (g4 + 3) * 16 + h * 4);
  float o0 = v0 * w0.x + v1 * w1.x + v2 * w2.x + v3 * w3.x;
  float o1 = v0 * w0.y + v1 * w1.y + v2 * w2.y + v3 * w3.y;
  float o2 = v0 * w0.z + v1 * w1.z + v2 * w2.z + v3 * w3.z;
  float o3 = v0 * w0.w + v1 * w1.w + v2 * w2.w + v3 * w3.w;
  #pragma unroll
  for (int mm = 1; mm < 16; mm <<= 1) {
    o0 += __shfl_xor(o0, mm); o1 += __shfl_xor(o1, mm);
    o2 += __shfl_xor(o2, mm); o3 += __shfl_xor(o3, mm);
  }
  if ((lane & 15) == 0) {
    float4 bcv = *(const float4*)(bcls + h * 4);
    float4 ov;
    ov.x = o0 + bcv.x; ov.y = o1 + bcv.y; ov.z = o2 + bcv.z; ov.w = o3 + bcv.w;
    *(float4*)(out + (size_t)n * 16 + h * 4) = ov;
  }
}

// ---------------------------------------------------------------------------
extern "C" void kernel_launch(void* const* d_in, const int* in_sizes, int n_in,
                              void* d_out, int out_size, void* d_ws, size_t ws_size,
                              hipStream_t stream)
{
  const float* x     = (const float*)d_in[0];
  const void*  ei    = d_in[1];
  const float* Win   = (const float*)d_in[2];
  const float* bin   = (const float*)d_in[3];
  const float* proto = (const float*)d_in[4];
  const float* Wl    = (const float*)d_in[5];
  const float* bl    = (const float*)d_in[6];
  const float* Wr    = (const float*)d_in[7];
  const float* br    = (const float*)d_in[8];
  const float* att   = (const float*)d_in[9];
  const float* gbias = (const float*)d_in[10];
  const float* wcls  = (const float*)d_in[11];
  const float* bcls  = (const float*)d_in[12];
  float* out = (float*)d_out;

  char* p = (char*)d_ws;
  size_t used = 0;
  auto carve = [&](size_t bytes) {
    char* q = p + used;
    used += (bytes + 255) & ~(size_t)255;
    return (void*)q;
  };
  int* gcount = (int*)carve(256);
  int* deg  = (int*)carve(N_NODES * 4);
  int* beg  = (int*)carve(N_NODES * 4);
  int* end  = (int*)carve(N_NODES * 4);
  int* cur  = (int*)carve(N_NODES * 4);
  int* esrc = (int*)carve(N_EDGES * 4);
  u16* wbT  = (u16*)carve(16384 * 2);
  u16* wlT  = (u16*)carve(24576 * 2);
  u16* wrT  = (u16*)carve(24576 * 2);
  float* ha = (float*)carve((size_t)N_NODES * 68 * 4 + 512);
  u16* xls  = (u16*)carve((size_t)N_NODES * 256 * 2);
  size_t used_min = used + ((size_t)N_NODES * 256 * 2);
  u16* xrs  = (u16*)carve((size_t)N_NODES * 256 * 2);
  const bool full = ws_size >= used_min;

  k_prep<<<196, 256, 0, stream>>>(Win, Wl, Wr, wbT, wlT, wrT, deg, gcount);
  k_haug<<<782, 256, 0, stream>>>(x, wbT, bin, proto, ha);
  k_hist<<<3125, 256, 0, stream>>>(ei, deg);
  k_lin<<<782, 256, 0, stream>>>(ha, wlT, bl, xls);
  if (full) k_lin<<<782, 256, 0, stream>>>(ha, wrT, br, xrs);
  k_scan1<<<NB_SCAN, 256, 0, stream>>>(deg, gcount, beg, end, cur);
  k_scatter<<<3125, 256, 0, stream>>>(ei, cur, esrc);
  if (full)
    k_agg<0><<<12500, 256, 0, stream>>>(xls, xrs, ha, Wr, br, esrc, beg, end,
                                        att, gbias, wcls, bcls, out);
  else
    k_agg<1><<<12500, 256, 0, stream>>>(xls, xrs, ha, Wr, br, esrc, beg, end,
                                        att, gbias, wcls, bcls, out);
}

// Round 11
// 323.922 us; speedup vs baseline: 1.0671x; 1.0671x over previous
//
#include <hip/hip_runtime.h>

#define N_NODES 50000
#define N_EDGES 800000
#define IN_DIM 256
#define HID 64
#define OUT_DIM 16
#define GAT_IN 66   // HID + N_PROTO
#define NB_SCAN 196 // 196*256 = 50176 >= N_NODES

typedef unsigned short u16;
typedef unsigned int u32;
typedef __attribute__((ext_vector_type(8))) short s8v;    // 8 bf16 (4 VGPRs)
typedef __attribute__((ext_vector_type(4))) float f4v;    // MFMA accumulator
typedef __attribute__((ext_vector_type(2))) _Float16 h2;  // packed f16 pair

__device__ __forceinline__ float bf2f(u16 u) {
  union { u32 i; float f; } v; v.i = ((u32)u) << 16; return v.f;
}
__device__ __forceinline__ u16 f2bf(float f) {
  union { float f; u32 i; } v; v.f = f;
  u32 r = v.i + 0x7FFFu + ((v.i >> 16) & 1u);
  return (u16)(r >> 16);
}
__device__ __forceinline__ u16 f2h(float f) {
  union { _Float16 h; u16 u; } v; v.h = (_Float16)f; return v.u;
}
__device__ __forceinline__ void split8(const float* uu, s8v& ah, s8v& al) {
  #pragma unroll
  for (int j = 0; j < 8; ++j) {
    u32 bits = __float_as_uint(uu[j]);
    u16 hb = (u16)(bits >> 16);
    ah[j] = (short)hb;
    al[j] = (short)f2bf(uu[j] - bf2f(hb));
  }
}

// ---------------------------------------------------------------------------
// K1 (MFMA): h = relu(x @ W_in + b_in); sem = cosine sim vs prototypes.
// Prologue zeroes deg[] and gcount. 512 threads = 8 waves x 16-node M-tile.
// W_in staged bf16 in LDS via coalesced float4 loads + inverse permutation.
// ---------------------------------------------------------------------------
__global__ __launch_bounds__(512) void k_haug(
    const float* __restrict__ x, const float* __restrict__ Win,
    const float* __restrict__ bin, const float* __restrict__ proto,
    float* __restrict__ ha, int* __restrict__ deg, int* __restrict__ gcount)
{
  for (int i = blockIdx.x * 512 + threadIdx.x; i < N_NODES; i += gridDim.x * 512)
    deg[i] = 0;
  if (blockIdx.x == 0 && threadIdx.x == 0) *gcount = 0;

  __shared__ u16 wb[8 * 4 * 64 * 8];  // 32 KB
  for (int w4 = threadIdx.x; w4 < 4096; w4 += 512) {
    int w = w4 * 4;
    float4 v = *(const float4*)(Win + w);
    int k = w >> 6, c0 = w & 63;
    int s = k >> 5, r5 = k & 31;
    int lh = r5 >> 3, j = r5 & 7;
    int t = c0 >> 4, l15 = c0 & 15;
    int m = s * 2048 + t * 512 + (lh * 16 + l15) * 8 + j;
    wb[m]      = f2bf(v.x);
    wb[m + 8]  = f2bf(v.y);
    wb[m + 16] = f2bf(v.z);
    wb[m + 24] = f2bf(v.w);
  }
  __syncthreads();
  const int lane = threadIdx.x & 63;
  const int nb = blockIdx.x * 128 + (threadIdx.x >> 6) * 16;
  if (nb >= N_NODES) return;
  const int mrow = lane & 15, q = lane >> 4;

  f4v acc0 = {0.f,0.f,0.f,0.f}, acc1 = {0.f,0.f,0.f,0.f};
  f4v acc2 = {0.f,0.f,0.f,0.f}, acc3 = {0.f,0.f,0.f,0.f};
  const float* xrow = x + (size_t)(nb + mrow) * IN_DIM + q * 8;
  #pragma unroll 2
  for (int s = 0; s < 8; ++s) {
    float4 u0 = *(const float4*)(xrow + s * 32);
    float4 u1 = *(const float4*)(xrow + s * 32 + 4);
    float uu[8] = {u0.x, u0.y, u0.z, u0.w, u1.x, u1.y, u1.z, u1.w};
    s8v ah, al;
    split8(uu, ah, al);
    const u16* wp = &wb[s * 2048 + lane * 8];
    s8v b0 = *(const s8v*)(wp);
    s8v b1 = *(const s8v*)(wp + 512);
    s8v b2 = *(const s8v*)(wp + 1024);
    s8v b3 = *(const s8v*)(wp + 1536);
    acc0 = __builtin_amdgcn_mfma_f32_16x16x32_bf16(ah, b0, acc0, 0, 0, 0);
    acc0 = __builtin_amdgcn_mfma_f32_16x16x32_bf16(al, b0, acc0, 0, 0, 0);
    acc1 = __builtin_amdgcn_mfma_f32_16x16x32_bf16(ah, b1, acc1, 0, 0, 0);
    acc1 = __builtin_amdgcn_mfma_f32_16x16x32_bf16(al, b1, acc1, 0, 0, 0);
    acc2 = __builtin_amdgcn_mfma_f32_16x16x32_bf16(ah, b2, acc2, 0, 0, 0);
    acc2 = __builtin_amdgcn_mfma_f32_16x16x32_bf16(al, b2, acc2, 0, 0, 0);
    acc3 = __builtin_amdgcn_mfma_f32_16x16x32_bf16(ah, b3, acc3, 0, 0, 0);
    acc3 = __builtin_amdgcn_mfma_f32_16x16x32_bf16(al, b3, acc3, 0, 0, 0);
  }

  float bt[4], p0t[4], p1t[4];
  #pragma unroll
  for (int t = 0; t < 4; ++t) {
    bt[t]  = bin[t * 16 + mrow];
    p0t[t] = proto[t * 16 + mrow];
    p1t[t] = proto[64 + t * 16 + mrow];
  }
  float np0 = 0.f, np1 = 0.f;
  #pragma unroll
  for (int t = 0; t < 4; ++t) { np0 += p0t[t] * p0t[t]; np1 += p1t[t] * p1t[t]; }
  #pragma unroll
  for (int mm = 1; mm < 16; mm <<= 1) {
    np0 += __shfl_xor(np0, mm); np1 += __shfl_xor(np1, mm);
  }
  const float ip0 = 1.f / (sqrtf(np0) + 1e-12f);
  const float ip1 = 1.f / (sqrtf(np1) + 1e-12f);

  float hcol[4][4];
  #pragma unroll
  for (int r = 0; r < 4; ++r) {
    hcol[0][r] = fmaxf(acc0[r] + bt[0], 0.f);
    hcol[1][r] = fmaxf(acc1[r] + bt[1], 0.f);
    hcol[2][r] = fmaxf(acc2[r] + bt[2], 0.f);
    hcol[3][r] = fmaxf(acc3[r] + bt[3], 0.f);
  }
  #pragma unroll
  for (int r = 0; r < 4; ++r) {
    float r0 = 0.f, r1 = 0.f, r2 = 0.f;
    #pragma unroll
    for (int t = 0; t < 4; ++t) {
      float h = hcol[t][r];
      r0 += h * h; r1 += h * p0t[t]; r2 += h * p1t[t];
    }
    #pragma unroll
    for (int mm = 1; mm < 16; mm <<= 1) {
      r0 += __shfl_xor(r0, mm); r1 += __shfl_xor(r1, mm); r2 += __shfl_xor(r2, mm);
    }
    float* row = ha + (size_t)(nb + q * 4 + r) * 68;
    #pragma unroll
    for (int t = 0; t < 4; ++t) row[t * 16 + mrow] = hcol[t][r];
    if (mrow == 0) {
      float hi = 1.f / (sqrtf(r0) + 1e-12f);
      row[64] = r1 * hi * ip0;
      row[65] = r2 * hi * ip1;
    }
  }
}

// ---------------------------------------------------------------------------
// K2 (MFMA): xl (or xr) = ha @ W + b -> **f16** [n][256] (col j = h*64+c).
// f16 output (more mantissa than bf16) feeds packed-f16 math in k_agg.
// ---------------------------------------------------------------------------
__global__ __launch_bounds__(512) void k_lin(
    const float* __restrict__ ha, const float* __restrict__ W,
    const float* __restrict__ b, u16* __restrict__ outp)
{
  __shared__ u16 wl[3 * 16 * 64 * 8];  // 48 KB
  for (int i = threadIdx.x; i < 4096; i += 512) ((u32*)wl)[8192 + i] = 0;
  __syncthreads();
  for (int w4 = threadIdx.x; w4 < 4224; w4 += 512) {
    int w = w4 * 4;
    float4 v = *(const float4*)(W + w);
    int k = w >> 8, j2 = w & 255;
    int s = k >> 5, r5 = k & 31;
    int lh = r5 >> 3, j = r5 & 7;
    int t = j2 >> 4, l15 = j2 & 15;
    int m = s * 8192 + t * 512 + (lh * 16 + l15) * 8 + j;
    wl[m]      = f2bf(v.x);
    wl[m + 8]  = f2bf(v.y);
    wl[m + 16] = f2bf(v.z);
    wl[m + 24] = f2bf(v.w);
  }
  __syncthreads();
  const int lane = threadIdx.x & 63;
  const int nb = blockIdx.x * 128 + (threadIdx.x >> 6) * 16;
  if (nb >= N_NODES) return;
  const int mrow = lane & 15, q = lane >> 4;

  f4v acc[16];
  #pragma unroll
  for (int t = 0; t < 16; ++t) acc[t] = (f4v){0.f, 0.f, 0.f, 0.f};

  const float* row = ha + (size_t)(nb + mrow) * 68;
  #pragma unroll
  for (int s = 0; s < 3; ++s) {
    float uu[8];
    if (s < 2) {
      float4 u0 = *(const float4*)(row + s * 32 + q * 8);
      float4 u1 = *(const float4*)(row + s * 32 + q * 8 + 4);
      uu[0]=u0.x; uu[1]=u0.y; uu[2]=u0.z; uu[3]=u0.w;
      uu[4]=u1.x; uu[5]=u1.y; uu[6]=u1.z; uu[7]=u1.w;
    } else {
      #pragma unroll
      for (int j = 0; j < 8; ++j) uu[j] = 0.f;
      if (q == 0) { uu[0] = row[64]; uu[1] = row[65]; }
    }
    s8v ah, al;
    split8(uu, ah, al);
    const u16* wp = &wl[s * 8192 + lane * 8];
    #pragma unroll
    for (int t = 0; t < 16; ++t) {
      s8v bv = *(const s8v*)(wp + t * 512);
      acc[t] = __builtin_amdgcn_mfma_f32_16x16x32_bf16(ah, bv, acc[t], 0, 0, 0);
      acc[t] = __builtin_amdgcn_mfma_f32_16x16x32_bf16(al, bv, acc[t], 0, 0, 0);
    }
  }

  #pragma unroll
  for (int t = 0; t < 16; ++t) {
    float bc = b[t * 16 + mrow];
    #pragma unroll
    for (int r = 0; r < 4; ++r) {
      outp[(size_t)(nb + q * 4 + r) * 256 + t * 16 + mrow] = f2h(acc[t][r] + bc);
    }
  }
}

// --------------------------- CSR construction ------------------------------
__device__ __forceinline__ int probe_i64(const void* ei) {
  const long long* e64 = (const long long*)ei;
  int ok = 1;
  #pragma unroll
  for (int k = 0; k < 16; k++) {
    long long v = e64[k];
    if (v < 0 || v >= N_NODES) { ok = 0; break; }
  }
  return ok;
}

__global__ void k_hist(const void* __restrict__ ei, int* __restrict__ deg) {
  __shared__ int isl_s;
  if (threadIdx.x == 0) isl_s = probe_i64(ei);
  __syncthreads();
  int e = blockIdx.x * 256 + threadIdx.x;
  if (e >= N_EDGES) return;
  int d;
  if (isl_s) d = (int)((const long long*)ei)[N_EDGES + e];
  else       d = ((const int*)ei)[N_EDGES + e];
  if ((unsigned)d < N_NODES) atomicAdd(&deg[d], 1);
}

__global__ __launch_bounds__(256) void k_scan1(
    const int* __restrict__ deg, int* __restrict__ gcount,
    int* __restrict__ beg, int* __restrict__ end, int* __restrict__ cur)
{
  const int t = threadIdx.x;
  const int lane = t & 63;
  const int i = blockIdx.x * 256 + t;
  int v = (i < N_NODES) ? deg[i] : 0;
  int inc = v;
  #pragma unroll
  for (int d = 1; d < 64; d <<= 1) {
    int sv = __shfl_up(inc, d);
    if (lane >= d) inc += sv;
  }
  __shared__ int wtot[4];
  __shared__ int base_s;
  if (lane == 63) wtot[t >> 6] = inc;
  __syncthreads();
  if (t == 0) {
    int tot = wtot[0] + wtot[1] + wtot[2] + wtot[3];
    base_s = atomicAdd(gcount, tot);
  }
  __syncthreads();
  int add = base_s;
  for (int w = 0; w < (t >> 6); ++w) add += wtot[w];
  int ex = add + inc - v;
  if (i < N_NODES) { beg[i] = ex; cur[i] = ex; end[i] = ex + v; }
}

__global__ void k_scatter(const void* __restrict__ ei,
                          int* __restrict__ cur, int* __restrict__ esrc) {
  __shared__ int isl_s;
  if (threadIdx.x == 0) isl_s = probe_i64(ei);
  __syncthreads();
  int e = blockIdx.x * 256 + threadIdx.x;
  if (e >= N_EDGES) return;
  int s, d;
  if (isl_s) {
    s = (int)((const long long*)ei)[e];
    d = (int)((const long long*)ei)[N_EDGES + e];
  } else {
    s = ((const int*)ei)[e];
    d = ((const int*)ei)[N_EDGES + e];
  }
  if ((unsigned)d >= N_NODES) return;
  if ((unsigned)s >= N_NODES) s = 0;
  int p = atomicAdd(&cur[d], 1);
  if ((unsigned)p < N_EDGES) esrc[p] = s;
}

// ---------------------------------------------------------------------------
// K5: per-dst-node softmax aggregation (no max-shift; clamp 60), unroll-4,
// packed-f16 channel math (v_pk_add/mul/max_f16 + v_dot2_f32_f16),
// + head-mean + relu + classifier. Head-major lane = (h, c4=(lane&15)*4).
// ---------------------------------------------------------------------------
__device__ __forceinline__ float edge_h(uint2 rv, h2 xr01, h2 xr23,
                                        h2 av01, h2 av23,
                                        h2& x01, h2& x23) {
  x01 = __builtin_bit_cast(h2, rv.x);
  x23 = __builtin_bit_cast(h2, rv.y);
  h2 t01 = x01 + xr01, t23 = x23 + xr23;
  t01 = __builtin_elementwise_max(t01, t01 * (_Float16)0.2f);
  t23 = __builtin_elementwise_max(t23, t23 * (_Float16)0.2f);
  float g = __builtin_amdgcn_fdot2(t01, av01, 0.f, false);
  return __builtin_amdgcn_fdot2(t23, av23, g, false);
}

template <int INLINE_XR>
__global__ __launch_bounds__(256) void k_agg(
    const u16* __restrict__ xls, const u16* __restrict__ xrs,
    const float* __restrict__ ha, const float* __restrict__ Wr,
    const float* __restrict__ br,
    const int* __restrict__ esrc, const int* __restrict__ beg,
    const int* __restrict__ end,
    const float* __restrict__ att, const float* __restrict__ gbias,
    const float* __restrict__ wcls, const float* __restrict__ bcls,
    float* __restrict__ out)
{
  __shared__ u16 wr[INLINE_XR ? GAT_IN * 256 : 64];
  if (INLINE_XR) {
    for (int m = threadIdx.x; m < GAT_IN * 256; m += 256) wr[m] = f2bf(Wr[m]);
    __syncthreads();
  }
  const int lane = threadIdx.x & 63;
  const int n = blockIdx.x * 4 + (threadIdx.x >> 6);
  if (n >= N_NODES) return;

  float4 avr = *(const float4*)(att + lane * 4);
  const h2 av01 = {(_Float16)avr.x, (_Float16)avr.y};
  const h2 av23 = {(_Float16)avr.z, (_Float16)avr.w};

  h2 xr01, xr23;
  if (INLINE_XR) {
    float4 bv = *(const float4*)(br + lane * 4);
    float y0 = bv.x, y1 = bv.y, y2 = bv.z, y3 = bv.w;
    const float* hrow = ha + (size_t)n * 68;
    for (int i = 0; i < GAT_IN; ++i) {
      ushort4 wv = *(const ushort4*)&wr[i * 256 + lane * 4];
      float hv = hrow[i];
      y0 += hv * bf2f(wv.x); y1 += hv * bf2f(wv.y);
      y2 += hv * bf2f(wv.z); y3 += hv * bf2f(wv.w);
    }
    xr01 = (h2){(_Float16)y0, (_Float16)y1};
    xr23 = (h2){(_Float16)y2, (_Float16)y3};
  } else {
    uint2 qv = *(const uint2*)(xrs + (size_t)n * 256 + lane * 4);
    xr01 = __builtin_bit_cast(h2, qv.x);
    xr23 = __builtin_bit_cast(h2, qv.y);
  }

  int kb = beg[n], ke = end[n];
  if (kb < 0) kb = 0;
  if (ke > N_EDGES) ke = N_EDGES;
  int dg = ke - kb; if (dg < 0) dg = 0;

  float l_, c0, c1, c2, c3;
  {  // self-loop
    uint2 rv = *(const uint2*)(xls + (size_t)n * 256 + lane * 4);
    h2 x01, x23;
    float g = edge_h(rv, xr01, xr23, av01, av23, x01, x23);
    g += __shfl_xor(g, 1); g += __shfl_xor(g, 2);
    g += __shfl_xor(g, 4); g += __shfl_xor(g, 8);
    float a = __expf(fminf(g, 60.f));
    l_ = a;
    c0 = a * (float)x01[0]; c1 = a * (float)x01[1];
    c2 = a * (float)x23[0]; c3 = a * (float)x23[1];
  }

  for (int e = 0; e < dg; e += 4) {
    const int rem = dg - e;
    const int i0 = kb + e;
    int s0 = esrc[i0];
    int s1 = (rem > 1) ? esrc[i0 + 1] : s0;
    int s2 = (rem > 2) ? esrc[i0 + 2] : s0;
    int s3 = (rem > 3) ? esrc[i0 + 3] : s0;
    uint2 r0 = *(const uint2*)(xls + (size_t)s0 * 256 + lane * 4);
    uint2 r1 = *(const uint2*)(xls + (size_t)s1 * 256 + lane * 4);
    uint2 r2 = *(const uint2*)(xls + (size_t)s2 * 256 + lane * 4);
    uint2 r3 = *(const uint2*)(xls + (size_t)s3 * 256 + lane * 4);
    h2 xa01, xa23, xb01, xb23, xc01, xc23, xd01, xd23;
    float g0 = edge_h(r0, xr01, xr23, av01, av23, xa01, xa23);
    float g1 = edge_h(r1, xr01, xr23, av01, av23, xb01, xb23);
    float g2 = edge_h(r2, xr01, xr23, av01, av23, xc01, xc23);
    float g3 = edge_h(r3, xr01, xr23, av01, av23, xd01, xd23);
    g0 += __shfl_xor(g0, 1); g1 += __shfl_xor(g1, 1);
    g2 += __shfl_xor(g2, 1); g3 += __shfl_xor(g3, 1);
    g0 += __shfl_xor(g0, 2); g1 += __shfl_xor(g1, 2);
    g2 += __shfl_xor(g2, 2); g3 += __shfl_xor(g3, 2);
    g0 += __shfl_xor(g0, 4); g1 += __shfl_xor(g1, 4);
    g2 += __shfl_xor(g2, 4); g3 += __shfl_xor(g3, 4);
    g0 += __shfl_xor(g0, 8); g1 += __shfl_xor(g1, 8);
    g2 += __shfl_xor(g2, 8); g3 += __shfl_xor(g3, 8);
    float a0 = __expf(fminf(g0, 60.f));
    float a1 = (rem > 1) ? __expf(fminf(g1, 60.f)) : 0.f;
    float a2 = (rem > 2) ? __expf(fminf(g2, 60.f)) : 0.f;
    float a3 = (rem > 3) ? __expf(fminf(g3, 60.f)) : 0.f;
    l_ += (a0 + a1) + (a2 + a3);
    c0 += a0 * (float)xa01[0] + a1 * (float)xb01[0]
        + a2 * (float)xc01[0] + a3 * (float)xd01[0];
    c1 += a0 * (float)xa01[1] + a1 * (float)xb01[1]
        + a2 * (float)xc01[1] + a3 * (float)xd01[1];
    c2 += a0 * (float)xa23[0] + a1 * (float)xb23[0]
        + a2 * (float)xc23[0] + a3 * (float)xd23[0];
    c3 += a0 * (float)xa23[1] + a1 * (float)xb23[1]
        + a2 * (float)xc23[1] + a3 * (float)xd23[1];
  }

  float inv = 1.f / (l_ + 1e-16f);
  float v0 = c0 * inv, v1 = c1 * inv, v2 = c2 * inv, v3 = c3 * inv;
  v0 += __shfl_xor(v0, 16); v0 += __shfl_xor(v0, 32);
  v1 += __shfl_xor(v1, 16); v1 += __shfl_xor(v1, 32);
  v2 += __shfl_xor(v2, 16); v2 += __shfl_xor(v2, 32);
  v3 += __shfl_xor(v3, 16); v3 += __shfl_xor(v3, 32);
  const int g4 = (lane & 15) * 4;
  const int h = lane >> 4;
  float4 gb = *(const float4*)(gbias + g4);
  v0 = fmaxf(0.25f * v0 + gb.x, 0.f);
  v1 = fmaxf(0.25f * v1 + gb.y, 0.f);
  v2 = fmaxf(0.25f * v2 + gb.z, 0.f);
  v3 = fmaxf(0.25f * v3 + gb.w, 0.f);
  float4 w0 = *(const float4*)(wcls + (g4 + 0) * 16 + h * 4);
  float4 w1 = *(const float4*)(wcls + (g4 + 1) * 16 + h * 4);
  float4 w2 = *(const float4*)(wcls + (g4 + 2) * 16 + h * 4);
  float4 w3 = *(const float4*)(wcls + (g4 + 3) * 16 + h * 4);
  float o0 = v0 * w0.x + v1 * w1.x + v2 * w2.x + v3 * w3.x;
  float o1 = v0 * w0.y + v1 * w1.y + v2 * w2.y + v3 * w3.y;
  float o2 = v0 * w0.z + v1 * w1.z + v2 * w2.z + v3 * w3.z;
  float o3 = v0 * w0.w + v1 * w1.w + v2 * w2.w + v3 * w3.w;
  #pragma unroll
  for (int mm = 1; mm < 16; mm <<= 1) {
    o0 += __shfl_xor(o0, mm); o1 += __shfl_xor(o1, mm);
    o2 += __shfl_xor(o2, mm); o3 += __shfl_xor(o3, mm);
  }
  if ((lane & 15) == 0) {
    float4 bcv = *(const float4*)(bcls + h * 4);
    float4 ov;
    ov.x = o0 + bcv.x; ov.y = o1 + bcv.y; ov.z = o2 + bcv.z; ov.w = o3 + bcv.w;
    *(float4*)(out + (size_t)n * 16 + h * 4) = ov;
  }
}

// ---------------------------------------------------------------------------
extern "C" void kernel_launch(void* const* d_in, const int* in_sizes, int n_in,
                              void* d_out, int out_size, void* d_ws, size_t ws_size,
                              hipStream_t stream)
{
  const float* x     = (const float*)d_in[0];
  const void*  ei    = d_in[1];
  const float* Win   = (const float*)d_in[2];
  const float* bin   = (const float*)d_in[3];
  const float* proto = (const float*)d_in[4];
  const float* Wl    = (const float*)d_in[5];
  const float* bl    = (const float*)d_in[6];
  const float* Wr    = (const float*)d_in[7];
  const float* br    = (const float*)d_in[8];
  const float* att   = (const float*)d_in[9];
  const float* gbias = (const float*)d_in[10];
  const float* wcls  = (const float*)d_in[11];
  const float* bcls  = (const float*)d_in[12];
  float* out = (float*)d_out;

  char* p = (char*)d_ws;
  size_t used = 0;
  auto carve = [&](size_t bytes) {
    char* q = p + used;
    used += (bytes + 255) & ~(size_t)255;
    return (void*)q;
  };
  int* gcount = (int*)carve(256);
  int* deg  = (int*)carve(N_NODES * 4);
  int* beg  = (int*)carve(N_NODES * 4);
  int* end  = (int*)carve(N_NODES * 4);
  int* cur  = (int*)carve(N_NODES * 4);
  int* esrc = (int*)carve(N_EDGES * 4);
  float* ha = (float*)carve((size_t)N_NODES * 68 * 4 + 512);
  u16* xls  = (u16*)carve((size_t)N_NODES * 256 * 2);
  size_t used_min = used + ((size_t)N_NODES * 256 * 2);
  u16* xrs  = (u16*)carve((size_t)N_NODES * 256 * 2);
  const bool full = ws_size >= used_min;

  k_haug<<<391, 512, 0, stream>>>(x, Win, bin, proto, ha, deg, gcount);
  k_hist<<<3125, 256, 0, stream>>>(ei, deg);
  k_lin<<<391, 512, 0, stream>>>(ha, Wl, bl, xls);
  if (full) k_lin<<<391, 512, 0, stream>>>(ha, Wr, br, xrs);
  k_scan1<<<NB_SCAN, 256, 0, stream>>>(deg, gcount, beg, end, cur);
  k_scatter<<<3125, 256, 0, stream>>>(ei, cur, esrc);
  if (full)
    k_agg<0><<<12500, 256, 0, stream>>>(xls, xrs, ha, Wr, br, esrc, beg, end,
                                        att, gbias, wcls, bcls, out);
  else
    k_agg<1><<<12500, 256, 0, stream>>>(xls, xrs, ha, Wr, br, esrc, beg, end,
                                        att, gbias, wcls, bcls, out);
}

// Round 12
// 315.456 us; speedup vs baseline: 1.0957x; 1.0268x over previous
//
#include <hip/hip_runtime.h>

#define N_NODES 50000
#define N_EDGES 800000
#define IN_DIM 256
#define HID 64
#define OUT_DIM 16
#define GAT_IN 66   // HID + N_PROTO
#define NB_SCAN 196 // 196*256 = 50176 >= N_NODES
#define HS_STRIDE 76  // LDS h-tile row stride (floats): 4-aligned, bank-spread

typedef unsigned short u16;
typedef unsigned int u32;
typedef __attribute__((ext_vector_type(8))) short s8v;    // 8 bf16 (4 VGPRs)
typedef __attribute__((ext_vector_type(4))) float f4v;    // MFMA accumulator
typedef __attribute__((ext_vector_type(2))) _Float16 h2;  // packed f16 pair

__device__ __forceinline__ float bf2f(u16 u) {
  union { u32 i; float f; } v; v.i = ((u32)u) << 16; return v.f;
}
__device__ __forceinline__ u16 f2bf(float f) {
  union { float f; u32 i; } v; v.f = f;
  u32 r = v.i + 0x7FFFu + ((v.i >> 16) & 1u);
  return (u16)(r >> 16);
}
__device__ __forceinline__ u16 f2h(float f) {
  union { _Float16 h; u16 u; } v; v.h = (_Float16)f; return v.u;
}
__device__ __forceinline__ void split8(const float* uu, s8v& ah, s8v& al) {
  #pragma unroll
  for (int j = 0; j < 8; ++j) {
    u32 bits = __float_as_uint(uu[j]);
    u16 hb = (u16)(bits >> 16);
    ah[j] = (short)hb;
    al[j] = (short)f2bf(uu[j] - bf2f(hb));
  }
}

// ---------------------------------------------------------------------------
// K_PREP: weights -> MFMA B-fragment order (bf16, global, L2-resident);
// zero deg[] / gcount. ~130 KB of writes, runs once per call.
// ---------------------------------------------------------------------------
__global__ __launch_bounds__(256) void k_prep(
    const float* __restrict__ Win, const float* __restrict__ Wl,
    const float* __restrict__ Wr, u16* __restrict__ wbT,
    u16* __restrict__ wlT, u16* __restrict__ wrT,
    int* __restrict__ deg, int* __restrict__ gcount)
{
  const int gid = blockIdx.x * 256 + threadIdx.x;
  const int stride = gridDim.x * 256;
  for (int i = gid; i < N_NODES; i += stride) deg[i] = 0;
  if (gid == 0) *gcount = 0;
  for (int m = gid; m < 16384; m += stride) {
    int s = m >> 11, rem = m & 2047;
    int t = rem >> 9, rem2 = rem & 511;
    int l = rem2 >> 3, j = rem2 & 7;
    int k = s * 32 + (l >> 4) * 8 + j;
    int c = t * 16 + (l & 15);
    wbT[m] = f2bf(Win[k * 64 + c]);
  }
  for (int m = gid; m < 24576; m += stride) {
    int s = m >> 13, rem = m & 8191;
    int t = rem >> 9, rem2 = rem & 511;
    int l = rem2 >> 3, j = rem2 & 7;
    int k = s * 32 + (l >> 4) * 8 + j;
    int j2 = t * 16 + (l & 15);
    u16 vl = 0, vr = 0;
    if (k < GAT_IN) {
      vl = f2bf(Wl[k * 256 + j2]);
      vr = f2bf(Wr[k * 256 + j2]);
    }
    wlT[m] = vl;
    wrT[m] = vr;
  }
}

// --------------------------- edge-dtype probe ------------------------------
__device__ __forceinline__ int probe_i64(const void* ei) {
  const long long* e64 = (const long long*)ei;
  int ok = 1;
  #pragma unroll
  for (int k = 0; k < 16; k++) {
    long long v = e64[k];
    if (v < 0 || v >= N_NODES) { ok = 0; break; }
  }
  return ok;
}

// ---------------------------------------------------------------------------
// K_MEGA: (1) edge histogram prologue; (2) h = relu(x@Win+b) + sem; (3) per-
// wave LDS transpose h -> A-fragments (built once); (4) xl = ha@Wl+bl -> f16;
// (5) xr = ha@Wr+br -> f16. B-fragments read from pre-transposed global
// tables (no LDS staging, no bank conflicts). One wave = one 16-node tile.
// ---------------------------------------------------------------------------
__global__ __launch_bounds__(256) void k_mega(
    const float* __restrict__ x, const void* __restrict__ ei,
    const u16* __restrict__ wbT, const float* __restrict__ bin,
    const float* __restrict__ proto,
    const u16* __restrict__ wlT, const float* __restrict__ bl,
    const u16* __restrict__ wrT, const float* __restrict__ br,
    float* __restrict__ ha, u16* __restrict__ xls, u16* __restrict__ xrs,
    int* __restrict__ deg)
{
  // ---- (1) histogram prologue (deg[] zeroed by k_prep) ----
  __shared__ int isl_s;
  if (threadIdx.x == 0) isl_s = probe_i64(ei);
  __syncthreads();
  {
    const int gid = blockIdx.x * 256 + threadIdx.x;
    const int stride = gridDim.x * 256;
    if (isl_s) {
      const long long* ed = (const long long*)ei + N_EDGES;
      for (int e = gid; e < N_EDGES; e += stride) {
        int d = (int)ed[e];
        if ((unsigned)d < N_NODES) atomicAdd(&deg[d], 1);
      }
    } else {
      const int* ed = (const int*)ei + N_EDGES;
      for (int e = gid; e < N_EDGES; e += stride) {
        int d = ed[e];
        if ((unsigned)d < N_NODES) atomicAdd(&deg[d], 1);
      }
    }
  }

  const int lane = threadIdx.x & 63;
  const int wv = threadIdx.x >> 6;
  const int nb = blockIdx.x * 64 + wv * 16;
  if (nb >= N_NODES) return;
  const int mrow = lane & 15, q = lane >> 4;

  __shared__ float hs_all[4][16 * HS_STRIDE];  // 19.5 KB, per-wave private
  float* hs = hs_all[wv];

  // ---- (2) h = relu(x @ Win + bin); sem = cosine sims ----
  f4v acc0 = {0.f,0.f,0.f,0.f}, acc1 = {0.f,0.f,0.f,0.f};
  f4v acc2 = {0.f,0.f,0.f,0.f}, acc3 = {0.f,0.f,0.f,0.f};
  const float* xrow = x + (size_t)(nb + mrow) * IN_DIM + q * 8;
  #pragma unroll 2
  for (int s = 0; s < 8; ++s) {
    float4 u0 = *(const float4*)(xrow + s * 32);
    float4 u1 = *(const float4*)(xrow + s * 32 + 4);
    float uu[8] = {u0.x, u0.y, u0.z, u0.w, u1.x, u1.y, u1.z, u1.w};
    s8v ah, al;
    split8(uu, ah, al);
    const u16* wp = wbT + s * 2048 + lane * 8;
    s8v b0 = *(const s8v*)(wp);
    s8v b1 = *(const s8v*)(wp + 512);
    s8v b2 = *(const s8v*)(wp + 1024);
    s8v b3 = *(const s8v*)(wp + 1536);
    acc0 = __builtin_amdgcn_mfma_f32_16x16x32_bf16(ah, b0, acc0, 0, 0, 0);
    acc0 = __builtin_amdgcn_mfma_f32_16x16x32_bf16(al, b0, acc0, 0, 0, 0);
    acc1 = __builtin_amdgcn_mfma_f32_16x16x32_bf16(ah, b1, acc1, 0, 0, 0);
    acc1 = __builtin_amdgcn_mfma_f32_16x16x32_bf16(al, b1, acc1, 0, 0, 0);
    acc2 = __builtin_amdgcn_mfma_f32_16x16x32_bf16(ah, b2, acc2, 0, 0, 0);
    acc2 = __builtin_amdgcn_mfma_f32_16x16x32_bf16(al, b2, acc2, 0, 0, 0);
    acc3 = __builtin_amdgcn_mfma_f32_16x16x32_bf16(ah, b3, acc3, 0, 0, 0);
    acc3 = __builtin_amdgcn_mfma_f32_16x16x32_bf16(al, b3, acc3, 0, 0, 0);
  }

  float bt[4], p0t[4], p1t[4];
  #pragma unroll
  for (int t = 0; t < 4; ++t) {
    bt[t]  = bin[t * 16 + mrow];
    p0t[t] = proto[t * 16 + mrow];
    p1t[t] = proto[64 + t * 16 + mrow];
  }
  float np0 = 0.f, np1 = 0.f;
  #pragma unroll
  for (int t = 0; t < 4; ++t) { np0 += p0t[t] * p0t[t]; np1 += p1t[t] * p1t[t]; }
  #pragma unroll
  for (int mm = 1; mm < 16; mm <<= 1) {
    np0 += __shfl_xor(np0, mm); np1 += __shfl_xor(np1, mm);
  }
  const float ip0 = 1.f / (sqrtf(np0) + 1e-12f);
  const float ip1 = 1.f / (sqrtf(np1) + 1e-12f);

  float hcol[4][4];
  #pragma unroll
  for (int r = 0; r < 4; ++r) {
    hcol[0][r] = fmaxf(acc0[r] + bt[0], 0.f);
    hcol[1][r] = fmaxf(acc1[r] + bt[1], 0.f);
    hcol[2][r] = fmaxf(acc2[r] + bt[2], 0.f);
    hcol[3][r] = fmaxf(acc3[r] + bt[3], 0.f);
  }
  #pragma unroll
  for (int r = 0; r < 4; ++r) {
    float r0 = 0.f, r1 = 0.f, r2 = 0.f;
    #pragma unroll
    for (int t = 0; t < 4; ++t) {
      float h = hcol[t][r];
      r0 += h * h; r1 += h * p0t[t]; r2 += h * p1t[t];
    }
    #pragma unroll
    for (int mm = 1; mm < 16; mm <<= 1) {
      r0 += __shfl_xor(r0, mm); r1 += __shfl_xor(r1, mm); r2 += __shfl_xor(r2, mm);
    }
    // write h-tile to per-wave LDS (2-way bank aliasing: free) + global ha
    const int node = q * 4 + r;
    float* row = ha + (size_t)(nb + node) * 68;
    #pragma unroll
    for (int t = 0; t < 4; ++t) {
      hs[node * HS_STRIDE + t * 16 + mrow] = hcol[t][r];
      row[t * 16 + mrow] = hcol[t][r];
    }
    if (mrow == 0) {
      float hi = 1.f / (sqrtf(r0) + 1e-12f);
      float s0 = r1 * hi * ip0, s1 = r2 * hi * ip1;
      hs[node * HS_STRIDE + 64] = s0;
      hs[node * HS_STRIDE + 65] = s1;
      row[64] = s0; row[65] = s1;
    }
  }

  // ---- (3) A-fragments from LDS h-tile (built once, reused for Wl and Wr)
  s8v ahs[3], als[3];
  #pragma unroll
  for (int s = 0; s < 3; ++s) {
    float uu[8];
    if (s < 2) {
      float4 u0 = *(const float4*)(hs + mrow * HS_STRIDE + s * 32 + q * 8);
      float4 u1 = *(const float4*)(hs + mrow * HS_STRIDE + s * 32 + q * 8 + 4);
      uu[0]=u0.x; uu[1]=u0.y; uu[2]=u0.z; uu[3]=u0.w;
      uu[4]=u1.x; uu[5]=u1.y; uu[6]=u1.z; uu[7]=u1.w;
    } else {
      #pragma unroll
      for (int j = 0; j < 8; ++j) uu[j] = 0.f;
      if (q == 0) {
        uu[0] = hs[mrow * HS_STRIDE + 64];
        uu[1] = hs[mrow * HS_STRIDE + 65];
      }
    }
    split8(uu, ahs[s], als[s]);
  }

  // ---- (4) xl = ha @ Wl + bl -> f16 ----
  #pragma unroll 2
  for (int t = 0; t < 16; ++t) {
    f4v acc = {0.f, 0.f, 0.f, 0.f};
    #pragma unroll
    for (int s = 0; s < 3; ++s) {
      s8v bv = *(const s8v*)(wlT + s * 8192 + t * 512 + lane * 8);
      acc = __builtin_amdgcn_mfma_f32_16x16x32_bf16(ahs[s], bv, acc, 0, 0, 0);
      acc = __builtin_amdgcn_mfma_f32_16x16x32_bf16(als[s], bv, acc, 0, 0, 0);
    }
    float bc = bl[t * 16 + mrow];
    #pragma unroll
    for (int r = 0; r < 4; ++r)
      xls[(size_t)(nb + q * 4 + r) * 256 + t * 16 + mrow] = f2h(acc[r] + bc);
  }

  // ---- (5) xr = ha @ Wr + br -> f16 ----
  #pragma unroll 2
  for (int t = 0; t < 16; ++t) {
    f4v acc = {0.f, 0.f, 0.f, 0.f};
    #pragma unroll
    for (int s = 0; s < 3; ++s) {
      s8v bv = *(const s8v*)(wrT + s * 8192 + t * 512 + lane * 8);
      acc = __builtin_amdgcn_mfma_f32_16x16x32_bf16(ahs[s], bv, acc, 0, 0, 0);
      acc = __builtin_amdgcn_mfma_f32_16x16x32_bf16(als[s], bv, acc, 0, 0, 0);
    }
    float bc = br[t * 16 + mrow];
    #pragma unroll
    for (int r = 0; r < 4; ++r)
      xrs[(size_t)(nb + q * 4 + r) * 256 + t * 16 + mrow] = f2h(acc[r] + bc);
  }
}

// --------------------------- CSR: scan + scatter ---------------------------
__global__ __launch_bounds__(256) void k_scan1(
    const int* __restrict__ deg, int* __restrict__ gcount,
    int* __restrict__ beg, int* __restrict__ end, int* __restrict__ cur)
{
  const int t = threadIdx.x;
  const int lane = t & 63;
  const int i = blockIdx.x * 256 + t;
  int v = (i < N_NODES) ? deg[i] : 0;
  int inc = v;
  #pragma unroll
  for (int d = 1; d < 64; d <<= 1) {
    int sv = __shfl_up(inc, d);
    if (lane >= d) inc += sv;
  }
  __shared__ int wtot[4];
  __shared__ int base_s;
  if (lane == 63) wtot[t >> 6] = inc;
  __syncthreads();
  if (t == 0) {
    int tot = wtot[0] + wtot[1] + wtot[2] + wtot[3];
    base_s = atomicAdd(gcount, tot);
  }
  __syncthreads();
  int add = base_s;
  for (int w = 0; w < (t >> 6); ++w) add += wtot[w];
  int ex = add + inc - v;
  if (i < N_NODES) { beg[i] = ex; cur[i] = ex; end[i] = ex + v; }
}

__global__ void k_scatter(const void* __restrict__ ei,
                          int* __restrict__ cur, int* __restrict__ esrc) {
  __shared__ int isl_s;
  if (threadIdx.x == 0) isl_s = probe_i64(ei);
  __syncthreads();
  int e = blockIdx.x * 256 + threadIdx.x;
  if (e >= N_EDGES) return;
  int s, d;
  if (isl_s) {
    s = (int)((const long long*)ei)[e];
    d = (int)((const long long*)ei)[N_EDGES + e];
  } else {
    s = ((const int*)ei)[e];
    d = ((const int*)ei)[N_EDGES + e];
  }
  if ((unsigned)d >= N_NODES) return;
  if ((unsigned)s >= N_NODES) s = 0;
  int p = atomicAdd(&cur[d], 1);
  if ((unsigned)p < N_EDGES) esrc[p] = s;
}

// ---------------------------------------------------------------------------
// K_AGG (unchanged from R11): per-dst-node softmax aggregation, unroll-4,
// packed-f16 channel math + head-mean + relu + classifier.
// ---------------------------------------------------------------------------
__device__ __forceinline__ float edge_h(uint2 rv, h2 xr01, h2 xr23,
                                        h2 av01, h2 av23,
                                        h2& x01, h2& x23) {
  x01 = __builtin_bit_cast(h2, rv.x);
  x23 = __builtin_bit_cast(h2, rv.y);
  h2 t01 = x01 + xr01, t23 = x23 + xr23;
  t01 = __builtin_elementwise_max(t01, t01 * (_Float16)0.2f);
  t23 = __builtin_elementwise_max(t23, t23 * (_Float16)0.2f);
  float g = __builtin_amdgcn_fdot2(t01, av01, 0.f, false);
  return __builtin_amdgcn_fdot2(t23, av23, g, false);
}

template <int INLINE_XR>
__global__ __launch_bounds__(256) void k_agg(
    const u16* __restrict__ xls, const u16* __restrict__ xrs,
    const float* __restrict__ ha, const float* __restrict__ Wr,
    const float* __restrict__ br,
    const int* __restrict__ esrc, const int* __restrict__ beg,
    const int* __restrict__ end,
    const float* __restrict__ att, const float* __restrict__ gbias,
    const float* __restrict__ wcls, const float* __restrict__ bcls,
    float* __restrict__ out)
{
  __shared__ u16 wr[INLINE_XR ? GAT_IN * 256 : 64];
  if (INLINE_XR) {
    for (int m = threadIdx.x; m < GAT_IN * 256; m += 256) wr[m] = f2bf(Wr[m]);
    __syncthreads();
  }
  const int lane = threadIdx.x & 63;
  const int n = blockIdx.x * 4 + (threadIdx.x >> 6);
  if (n >= N_NODES) return;

  float4 avr = *(const float4*)(att + lane * 4);
  const h2 av01 = {(_Float16)avr.x, (_Float16)avr.y};
  const h2 av23 = {(_Float16)avr.z, (_Float16)avr.w};

  h2 xr01, xr23;
  if (INLINE_XR) {
    float4 bv = *(const float4*)(br + lane * 4);
    float y0 = bv.x, y1 = bv.y, y2 = bv.z, y3 = bv.w;
    const float* hrow = ha + (size_t)n * 68;
    for (int i = 0; i < GAT_IN; ++i) {
      ushort4 wv = *(const ushort4*)&wr[i * 256 + lane * 4];
      float hv = hrow[i];
      y0 += hv * bf2f(wv.x); y1 += hv * bf2f(wv.y);
      y2 += hv * bf2f(wv.z); y3 += hv * bf2f(wv.w);
    }
    xr01 = (h2){(_Float16)y0, (_Float16)y1};
    xr23 = (h2){(_Float16)y2, (_Float16)y3};
  } else {
    uint2 qv = *(const uint2*)(xrs + (size_t)n * 256 + lane * 4);
    xr01 = __builtin_bit_cast(h2, qv.x);
    xr23 = __builtin_bit_cast(h2, qv.y);
  }

  int kb = beg[n], ke = end[n];
  if (kb < 0) kb = 0;
  if (ke > N_EDGES) ke = N_EDGES;
  int dg = ke - kb; if (dg < 0) dg = 0;

  float l_, c0, c1, c2, c3;
  {  // self-loop
    uint2 rv = *(const uint2*)(xls + (size_t)n * 256 + lane * 4);
    h2 x01, x23;
    float g = edge_h(rv, xr01, xr23, av01, av23, x01, x23);
    g += __shfl_xor(g, 1); g += __shfl_xor(g, 2);
    g += __shfl_xor(g, 4); g += __shfl_xor(g, 8);
    float a = __expf(fminf(g, 60.f));
    l_ = a;
    c0 = a * (float)x01[0]; c1 = a * (float)x01[1];
    c2 = a * (float)x23[0]; c3 = a * (float)x23[1];
  }

  for (int e = 0; e < dg; e += 4) {
    const int rem = dg - e;
    const int i0 = kb + e;
    int s0 = esrc[i0];
    int s1 = (rem > 1) ? esrc[i0 + 1] : s0;
    int s2 = (rem > 2) ? esrc[i0 + 2] : s0;
    int s3 = (rem > 3) ? esrc[i0 + 3] : s0;
    uint2 r0 = *(const uint2*)(xls + (size_t)s0 * 256 + lane * 4);
    uint2 r1 = *(const uint2*)(xls + (size_t)s1 * 256 + lane * 4);
    uint2 r2 = *(const uint2*)(xls + (size_t)s2 * 256 + lane * 4);
    uint2 r3 = *(const uint2*)(xls + (size_t)s3 * 256 + lane * 4);
    h2 xa01, xa23, xb01, xb23, xc01, xc23, xd01, xd23;
    float g0 = edge_h(r0, xr01, xr23, av01, av23, xa01, xa23);
    float g1 = edge_h(r1, xr01, xr23, av01, av23, xb01, xb23);
    float g2 = edge_h(r2, xr01, xr23, av01, av23, xc01, xc23);
    float g3 = edge_h(r3, xr01, xr23, av01, av23, xd01, xd23);
    g0 += __shfl_xor(g0, 1); g1 += __shfl_xor(g1, 1);
    g2 += __shfl_xor(g2, 1); g3 += __shfl_xor(g3, 1);
    g0 += __shfl_xor(g0, 2); g1 += __shfl_xor(g1, 2);
    g2 += __shfl_xor(g2, 2); g3 += __shfl_xor(g3, 2);
    g0 += __shfl_xor(g0, 4); g1 += __shfl_xor(g1, 4);
    g2 += __shfl_xor(g2, 4); g3 += __shfl_xor(g3, 4);
    g0 += __shfl_xor(g0, 8); g1 += __shfl_xor(g1, 8);
    g2 += __shfl_xor(g2, 8); g3 += __shfl_xor(g3, 8);
    float a0 = __expf(fminf(g0, 60.f));
    float a1 = (rem > 1) ? __expf(fminf(g1, 60.f)) : 0.f;
    float a2 = (rem > 2) ? __expf(fminf(g2, 60.f)) : 0.f;
    float a3 = (rem > 3) ? __expf(fminf(g3, 60.f)) : 0.f;
    l_ += (a0 + a1) + (a2 + a3);
    c0 += a0 * (float)xa01[0] + a1 * (float)xb01[0]
        + a2 * (float)xc01[0] + a3 * (float)xd01[0];
    c1 += a0 * (float)xa01[1] + a1 * (float)xb01[1]
        + a2 * (float)xc01[1] + a3 * (float)xd01[1];
    c2 += a0 * (float)xa23[0] + a1 * (float)xb23[0]
        + a2 * (float)xc23[0] + a3 * (float)xd23[0];
    c3 += a0 * (float)xa23[1] + a1 * (float)xb23[1]
        + a2 * (float)xc23[1] + a3 * (float)xd23[1];
  }

  float inv = 1.f / (l_ + 1e-16f);
  float v0 = c0 * inv, v1 = c1 * inv, v2 = c2 * inv, v3 = c3 * inv;
  v0 += __shfl_xor(v0, 16); v0 += __shfl_xor(v0, 32);
  v1 += __shfl_xor(v1, 16); v1 += __shfl_xor(v1, 32);
  v2 += __shfl_xor(v2, 16); v2 += __shfl_xor(v2, 32);
  v3 += __shfl_xor(v3, 16); v3 += __shfl_xor(v3, 32);
  const int g4 = (lane & 15) * 4;
  const int h = lane >> 4;
  float4 gb = *(const float4*)(gbias + g4);
  v0 = fmaxf(0.25f * v0 + gb.x, 0.f);
  v1 = fmaxf(0.25f * v1 + gb.y, 0.f);
  v2 = fmaxf(0.25f * v2 + gb.z, 0.f);
  v3 = fmaxf(0.25f * v3 + gb.w, 0.f);
  float4 w0 = *(const float4*)(wcls + (g4 + 0) * 16 + h * 4);
  float4 w1 = *(const float4*)(wcls + (g4 + 1) * 16 + h * 4);
  float4 w2 = *(const float4*)(wcls + (g4 + 2) * 16 + h * 4);
  float4 w3 = *(const float4*)(wcls + (g4 + 3) * 16 + h * 4);
  float o0 = v0 * w0.x + v1 * w1.x + v2 * w2.x + v3 * w3.x;
  float o1 = v0 * w0.y + v1 * w1.y + v2 * w2.y + v3 * w3.y;
  float o2 = v0 * w0.z + v1 * w1.z + v2 * w2.z + v3 * w3.z;
  float o3 = v0 * w0.w + v1 * w1.w + v2 * w2.w + v3 * w3.w;
  #pragma unroll
  for (int mm = 1; mm < 16; mm <<= 1) {
    o0 += __shfl_xor(o0, mm); o1 += __shfl_xor(o1, mm);
    o2 += __shfl_xor(o2, mm); o3 += __shfl_xor(o3, mm);
  }
  if ((lane & 15) == 0) {
    float4 bcv = *(const float4*)(bcls + h * 4);
    float4 ov;
    ov.x = o0 + bcv.x; ov.y = o1 + bcv.y; ov.z = o2 + bcv.z; ov.w = o3 + bcv.w;
    *(float4*)(out + (size_t)n * 16 + h * 4) = ov;
  }
}

// ---------------------------------------------------------------------------
extern "C" void kernel_launch(void* const* d_in, const int* in_sizes, int n_in,
                              void* d_out, int out_size, void* d_ws, size_t ws_size,
                              hipStream_t stream)
{
  const float* x     = (const float*)d_in[0];
  const void*  ei    = d_in[1];
  const float* Win   = (const float*)d_in[2];
  const float* bin   = (const float*)d_in[3];
  const float* proto = (const float*)d_in[4];
  const float* Wl    = (const float*)d_in[5];
  const float* bl    = (const float*)d_in[6];
  const float* Wr    = (const float*)d_in[7];
  const float* br    = (const float*)d_in[8];
  const float* att   = (const float*)d_in[9];
  const float* gbias = (const float*)d_in[10];
  const float* wcls  = (const float*)d_in[11];
  const float* bcls  = (const float*)d_in[12];
  float* out = (float*)d_out;

  char* p = (char*)d_ws;
  size_t used = 0;
  auto carve = [&](size_t bytes) {
    char* q = p + used;
    used += (bytes + 255) & ~(size_t)255;
    return (void*)q;
  };
  int* gcount = (int*)carve(256);
  int* deg  = (int*)carve(N_NODES * 4);
  int* beg  = (int*)carve(N_NODES * 4);
  int* end  = (int*)carve(N_NODES * 4);
  int* cur  = (int*)carve(N_NODES * 4);
  int* esrc = (int*)carve(N_EDGES * 4);
  u16* wbT  = (u16*)carve(16384 * 2);
  u16* wlT  = (u16*)carve(24576 * 2);
  u16* wrT  = (u16*)carve(24576 * 2);
  float* ha = (float*)carve((size_t)N_NODES * 68 * 4 + 512);
  u16* xls  = (u16*)carve((size_t)N_NODES * 256 * 2);
  size_t used_min = used + ((size_t)N_NODES * 256 * 2);
  u16* xrs  = (u16*)carve((size_t)N_NODES * 256 * 2);
  const bool full = ws_size >= used_min;

  k_prep<<<196, 256, 0, stream>>>(Win, Wl, Wr, wbT, wlT, wrT, deg, gcount);
  k_mega<<<782, 256, 0, stream>>>(x, ei, wbT, bin, proto, wlT, bl, wrT, br,
                                  ha, xls, xrs, deg);
  k_scan1<<<NB_SCAN, 256, 0, stream>>>(deg, gcount, beg, end, cur);
  k_scatter<<<3125, 256, 0, stream>>>(ei, cur, esrc);
  if (full)
    k_agg<0><<<12500, 256, 0, stream>>>(xls, xrs, ha, Wr, br, esrc, beg, end,
                                        att, gbias, wcls, bcls, out);
  else
    k_agg<1><<<12500, 256, 0, stream>>>(xls, xrs, ha, Wr, br, esrc, beg, end,
                                        att, gbias, wcls, bcls, out);
}